// Round 11
// baseline (40.761 us; speedup 1.0000x reference)
//
#include <hip/hip_runtime.h>
#include <cstdint>

namespace {
constexpr int T = 1024;
constexpr int B = 8;
constexpr int D = 512;
constexpr int W = 32;
constexpr int M = T * B; // 8192 rows (t*B+b)
}

using half8  = __attribute__((ext_vector_type(8))) _Float16;
using f32x16 = __attribute__((ext_vector_type(16))) float;

__device__ __forceinline__ void gload16(const void* g, void* l) {
    __builtin_amdgcn_global_load_lds(
        (const __attribute__((address_space(1))) void*)g,
        (__attribute__((address_space(3))) void*)l, 16, 0, 0);
}

__device__ __forceinline__ float fast_tanh(float x) {
    float e = __expf(2.f * x);
    return 1.f - 2.f / (e + 1.f);
}

// ---- prep_slim: ONLY the W transpose (fp32 [e][d] -> fp16 Bt [d][e]), 64 blocks.
// X conversion moved into gemm (self-staged A); Ah is produced by gemm's
// nb==0 blocks.
__global__ __launch_bounds__(256) void prep_slim(
    const float* __restrict__ Wm, _Float16* __restrict__ Bt)
{
    __shared__ float tile[64][65];
    const int tid = threadIdx.x;
    const int bid = blockIdx.x;
    const int bd = bid & 7;
    const int be = bid >> 3;
    const int r  = tid >> 2;
    const int c0 = (tid & 3) * 16;
    const float* src = Wm + (size_t)(be * 64 + r) * 512 + bd * 64 + c0;
#pragma unroll
    for (int j = 0; j < 16; j += 4) {
        const float4 v = *reinterpret_cast<const float4*>(src + j);
        tile[r][c0 + j]     = v.x;
        tile[r][c0 + j + 1] = v.y;
        tile[r][c0 + j + 2] = v.z;
        tile[r][c0 + j + 3] = v.w;
    }
    __syncthreads();
    const int dd = tid >> 2;
    const int e0 = (tid & 3) * 16;
    half8 h0, h1;
#pragma unroll
    for (int j = 0; j < 8; ++j)  h0[j] = (_Float16)tile[e0 + j][dd];
#pragma unroll
    for (int j = 0; j < 8; ++j)  h1[j] = (_Float16)tile[e0 + 8 + j][dd];
    _Float16* dst = Bt + (size_t)(bd * 64 + dd) * 512 + be * 64 + e0;
    *reinterpret_cast<half8*>(dst)     = h0;
    *reinterpret_cast<half8*>(dst + 8) = h1;
}

// ---- GEMM + tanh + proj-dot -> spart[8][M]; also writes Ah (nb==0 blocks).
// A-operand self-staged from X fp32 (reg load -> cvt fp16 -> ds_write_b128 to
// the SAME swizzled LDS offsets as before; fragments/MFMA unchanged).
// B via gload16 from Bt. Counted vmcnt: per stage issue A(4 loads) then B(4
// gload16); top-of-loop vmcnt(8) retires B(kt); post-MFMA vmcnt(4) retires
// A(kt+1) regs (in-order FIFO). Tile 64x128, 512 blocks, 2 blk/CU.
__global__ __launch_bounds__(256) void gemm_scores(
    const float* __restrict__ X, const _Float16* __restrict__ Bt,
    const float* __restrict__ proj, float* __restrict__ spart,
    _Float16* __restrict__ Ah)
{
    __shared__ char lds_buf[49152]; // [2 bufs][A 8K | B 16K]

    const int tid  = threadIdx.x;
    const int lane = tid & 63;
    const int wv   = tid >> 6;
    const int wm   = wv >> 1;
    const int wn   = wv & 1;
    const int hi   = lane >> 5;
    const int l31  = lane & 31;
    const int l7   = lane & 7;

    const int bid  = blockIdx.x;
    const int wgid = (bid & 7) * 64 + (bid >> 3); // XCD-aware swizzle
    const int mb   = wgid >> 2;
    const int nb   = wgid & 3;
    const int m0   = mb * 64;
    const int n0   = nb * 128;
    const bool storeAh = (nb == 0); // each row panel written exactly once

    const int wbase = __builtin_amdgcn_readfirstlane(tid & ~63);

    // this thread's two A chunks (fixed across kt): chunk c = i*256+tid
    const int rowA0c = (tid) >> 3,        chA0 = tid & 7;
    const int rowA1c = (256 + tid) >> 3,  chA1 = (256 + tid) & 7;
    const int swzA0  = (chA0 ^ (rowA0c & 7)) << 3; // halfword offset in row
    const int swzA1  = (chA1 ^ (rowA1c & 7)) << 3;

    f32x16 acc0 = {}, acc1 = {};
    float4 areg[4]; // A(kt+1) staging regs: {chunk0 lo, chunk0 hi, chunk1 lo, chunk1 hi}

    auto issueA = [&](int kt) {
        const int kbase = kt * 64;
        const float* s0 = X + (size_t)(m0 + rowA0c) * 512 + kbase + swzA0;
        const float* s1 = X + (size_t)(m0 + rowA1c) * 512 + kbase + swzA1;
        areg[0] = *reinterpret_cast<const float4*>(s0);
        areg[1] = *reinterpret_cast<const float4*>(s0 + 4);
        areg[2] = *reinterpret_cast<const float4*>(s1);
        areg[3] = *reinterpret_cast<const float4*>(s1 + 4);
    };
    auto issueB = [&](int bufi, int kt) {
        char* bbase = lds_buf + bufi * 24576 + 8192;
        const int kbase = kt * 64;
#pragma unroll
        for (int i = 0; i < 4; ++i) {
            const int c   = i * 256 + tid;
            const int row = c >> 3;
            const int ch  = c & 7;
            const int koff = kbase + ((ch ^ (row & 7)) << 3);
            gload16(Bt + (size_t)(n0 + row) * 512 + koff,
                    bbase + (size_t)(i * 256 + wbase) * 16);
        }
    };
    auto writeA = [&](int bufi, int kt) {
        char* abase = lds_buf + bufi * 24576;
        half8 h0, h1;
#pragma unroll
        for (int j = 0; j < 4; ++j) {
            h0[j]     = (_Float16)areg[0][j];
            h0[4 + j] = (_Float16)areg[1][j];
            h1[j]     = (_Float16)areg[2][j];
            h1[4 + j] = (_Float16)areg[3][j];
        }
        *reinterpret_cast<half8*>(abase + (size_t)tid * 16)         = h0;
        *reinterpret_cast<half8*>(abase + (size_t)(256 + tid) * 16) = h1;
        if (storeAh) {
            const int kbase = kt * 64;
            *reinterpret_cast<half8*>(Ah + (size_t)(m0 + rowA0c) * 512 + kbase + swzA0) = h0;
            *reinterpret_cast<half8*>(Ah + (size_t)(m0 + rowA1c) * 512 + kbase + swzA1) = h1;
        }
    };

    // prologue: tile 0
    issueA(0);
    issueB(0, 0);
    writeA(0, 0); // compiler waits the 4 A-loads (B's 4 gload16 stay in flight)

    int cur = 0;
    const int rowA  = wm * 32 + l31;
    const int colB0 = wn * 64 + l31;
    const int colB1 = colB0 + 32;

    for (int kt = 0; kt < 8; ++kt) {
        if (kt < 7) {
            issueA(kt + 1);                      // +4 loads (regs)
            issueB(cur ^ 1, kt + 1);             // +4 gload16
            asm volatile("s_waitcnt vmcnt(8)" ::: "memory"); // B(kt) landed
        } else {
            asm volatile("s_waitcnt vmcnt(0)" ::: "memory");
        }
        __syncthreads(); // buf[cur] fully ready (A ds_written prev iter, B DMA)

        const char* Ab = lds_buf + cur * 24576;
        const char* Bb = Ab + 8192;

        half8 af[4], bf0[4], bf1[4];
#pragma unroll
        for (int s = 0; s < 4; ++s) {
            const int ch = ((2 * s + hi) ^ l7) << 4;
            af[s]  = *reinterpret_cast<const half8*>(Ab + rowA  * 128 + ch);
            bf0[s] = *reinterpret_cast<const half8*>(Bb + colB0 * 128 + ch);
            bf1[s] = *reinterpret_cast<const half8*>(Bb + colB1 * 128 + ch);
        }
        __builtin_amdgcn_s_setprio(1);
#pragma unroll
        for (int s = 0; s < 4; ++s) {
            acc0 = __builtin_amdgcn_mfma_f32_32x32x16_f16(af[s], bf0[s], acc0, 0, 0, 0);
            acc1 = __builtin_amdgcn_mfma_f32_32x32x16_f16(af[s], bf1[s], acc1, 0, 0, 0);
        }
        __builtin_amdgcn_s_setprio(0);

        if (kt < 7) {
            asm volatile("s_waitcnt vmcnt(4)" ::: "memory"); // A(kt+1) regs landed
            writeA(cur ^ 1, kt + 1);             // cvt + ds_write (+Ah store)
        }
        __syncthreads(); // reads of buf[cur] done before it is restaged
        cur ^= 1;
    }

    const float pj0 = proj[n0 + wn * 64 + l31];
    const float pj1 = proj[n0 + wn * 64 + 32 + l31];
    float* sp = spart + (size_t)(nb * 2 + wn) * M;

#pragma unroll
    for (int reg = 0; reg < 16; ++reg) {
        float v0 = fast_tanh(acc0[reg]) * pj0 + fast_tanh(acc1[reg]) * pj1;
#pragma unroll
        for (int msk = 1; msk < 32; msk <<= 1)
            v0 += __shfl_xor(v0, msk, 64);
        if (l31 == 0) {
            const int rl = (reg & 3) + 8 * (reg >> 2) + 4 * hi;
            sp[m0 + wm * 32 + rl] = v0;
        }
    }
}

// ---- attend: round-9 v2 VERBATIM (16-row halves, LDS window staging —
// round-10 showed removing it costs +2.4 µs: grid already gives 2 blk/CU,
// staging shares the window across 4 waves) ----
__global__ __launch_bounds__(256) void attend_kernel(
    const float* __restrict__ X, const _Float16* __restrict__ Ah,
    const float* __restrict__ spart, float* __restrict__ out)
{
    __shared__ char lds[49152];
    _Float16* W_lds = reinterpret_cast<_Float16*>(lds);      // 47*512 fp16
    float*    p_lds = reinterpret_cast<float*>(lds + 48128); // 47 floats

    const int vb  = blockIdx.x;
    const int tid = threadIdx.x;
    const int ih  = vb & 1;
    const int b   = (vb >> 1) & 7;
    const int ig  = vb >> 4;
    const int i0  = ig * 32 + ih * 16;

    if (ig == 0) { // outputs < 32: exact fp32 passthrough
        const float4* X4 = reinterpret_cast<const float4*>(X);
        float4* O4 = reinterpret_cast<float4*>(out);
        for (int idx = tid; idx < 16 * 128; idx += 256) {
            const int r = idx >> 7;
            const int c = idx & 127;
            const size_t off = (size_t)((i0 + r) * 8 + b) * 128 + c;
            O4[off] = X4[off];
        }
        return;
    }

    const int tau0 = i0 - 32;
    const int lane = tid & 63;
    const int wbase = __builtin_amdgcn_readfirstlane(tid & ~63);

    // stage 47 window rows -> W_lds (3008 x 16B chunks; 3008 % 64 == 0)
    {
        const _Float16* src = Ah + (size_t)(tau0 * 8 + b) * 512;
#pragma unroll
        for (int it = 0; it < 12; ++it) {
            const int cbase = it * 256 + wbase;   // wave-uniform chunk base
            if (cbase < 3008) {
                const int c  = cbase + lane;
                const int r  = c >> 6;
                const int ch = c & 63;
                gload16(src + (size_t)r * 4096 + ch * 8,
                        (char*)W_lds + (size_t)cbase * 16);
            }
        }
    }

    // softmax weights for lt in [0,47)
    const int bj = tid & 7;
#pragma unroll
    for (int half = 0; half < 2; ++half) {
        const int lt = (tid >> 3) + half * 32;
        if (lt < 47) {
            float s = 0.f;
#pragma unroll
            for (int g = 0; g < 8; ++g)
                s += spart[(size_t)g * M + (size_t)(tau0 + lt) * 8 + bj];
            float mx = s;
#pragma unroll
            for (int msk = 1; msk < 8; msk <<= 1)
                mx = fmaxf(mx, __shfl_xor(mx, msk, 64));
            const float e = __expf(s - mx);
            float sum = e;
#pragma unroll
            for (int msk = 1; msk < 8; msk <<= 1)
                sum += __shfl_xor(sum, msk, 64);
            if (bj == b) p_lds[lt] = e / sum;
        }
    }

    asm volatile("s_waitcnt vmcnt(0)" ::: "memory");
    __syncthreads();

    // wave rg owns output rows i0+u0+q, q=0..3 (u0 = rg*4); window rows
    // lt = u0+u, u in [0,35); row feeds output q iff k = u-q in [0,32).
    const int rg = tid >> 6;
    const int u0 = rg * 4;
    float acc[4][8];
#pragma unroll
    for (int q = 0; q < 4; ++q)
#pragma unroll
        for (int j = 0; j < 8; ++j) acc[q][j] = 0.f;

    auto apply = [&](int u, int qlo, int qhi) {
        const int lt = u0 + u;
        const float pw = p_lds[lt];
        const half8 h = *reinterpret_cast<const half8*>(
            W_lds + (size_t)lt * 512 + lane * 8);
        float hf[8];
#pragma unroll
        for (int j = 0; j < 8; ++j) hf[j] = (float)h[j];
        for (int q = qlo; q <= qhi; ++q)
#pragma unroll
            for (int j = 0; j < 8; ++j)
                acc[q][j] = fmaf(pw, hf[j], acc[q][j]);
    };

#pragma unroll
    for (int u = 0; u < 3; ++u)  apply(u, 0, u);        // head: q <= u
    for (int u = 3; u < 32; ++u) apply(u, 0, 3);        // body: all q
#pragma unroll
    for (int u = 32; u < 35; ++u) apply(u, u - 31, 3);  // tail: q >= u-31

#pragma unroll
    for (int q = 0; q < 4; ++q) {
        float4* O4 = reinterpret_cast<float4*>(
            out + (size_t)((i0 + u0 + q) * 8 + b) * 512 + lane * 8);
        O4[0] = float4{acc[q][0], acc[q][1], acc[q][2], acc[q][3]};
        O4[1] = float4{acc[q][4], acc[q][5], acc[q][6], acc[q][7]};
    }
}

extern "C" void kernel_launch(void* const* d_in, const int* in_sizes, int n_in,
                              void* d_out, int out_size, void* d_ws, size_t ws_size,
                              hipStream_t stream)
{
    const float* X    = (const float*)d_in[0];
    const float* Wm   = (const float*)d_in[1];
    const float* proj = (const float*)d_in[2];
    float* out = (float*)d_out;

    _Float16* Ah   = (_Float16*)d_ws;              // 8 MB (written by gemm nb==0)
    _Float16* Bt   = Ah + (size_t)M * D;           // 0.5 MB
    float*    sprt = (float*)(Bt + (size_t)D * D); // 8*M floats

    prep_slim<<<64, 256, 0, stream>>>(Wm, Bt);
    gemm_scores<<<512, 256, 0, stream>>>(X, Bt, proj, sprt, Ah);
    attend_kernel<<<(T / W) * B * 2, 256, 0, stream>>>(X, Ah, sprt, out);
}

// Round 12
// 37.495 us; speedup vs baseline: 1.0871x; 1.0871x over previous
//
#include <hip/hip_runtime.h>
#include <cstdint>

namespace {
constexpr int T = 1024;
constexpr int B = 8;
constexpr int D = 512;
constexpr int W = 32;
constexpr int M = T * B; // 8192 rows (t*B+b)
}

using half8  = __attribute__((ext_vector_type(8))) _Float16;
using f32x16 = __attribute__((ext_vector_type(16))) float;

__device__ __forceinline__ void gload16(const void* g, void* l) {
    __builtin_amdgcn_global_load_lds(
        (const __attribute__((address_space(1))) void*)g,
        (__attribute__((address_space(3))) void*)l, 16, 0, 0);
}

__device__ __forceinline__ float fast_tanh(float x) {
    float e = __expf(2.f * x);
    return 1.f - 2.f / (e + 1.f);
}

// ---- prep: X fp32 -> Ah fp16 [M][D] (all blocks); W -> Bt^T (blocks 0..63) ----
// (round-9 verbatim)
__global__ __launch_bounds__(256) void prep_merged(
    const float* __restrict__ X, const float* __restrict__ Wm,
    _Float16* __restrict__ Ah, _Float16* __restrict__ Bt)
{
    __shared__ float tile[64][65];
    const int tid = threadIdx.x;
    const int bid = blockIdx.x;

    {
        const int c = bid * 256 + tid;
        const float4* X4 = reinterpret_cast<const float4*>(X);
        const float4 v0 = X4[(size_t)c * 2];
        const float4 v1 = X4[(size_t)c * 2 + 1];
        half8 h;
        h[0] = (_Float16)v0.x; h[1] = (_Float16)v0.y; h[2] = (_Float16)v0.z; h[3] = (_Float16)v0.w;
        h[4] = (_Float16)v1.x; h[5] = (_Float16)v1.y; h[6] = (_Float16)v1.z; h[7] = (_Float16)v1.w;
        *reinterpret_cast<half8*>(Ah + (size_t)c * 8) = h;
    }

    if (bid < 64) {
        const int bd = bid & 7;
        const int be = bid >> 3;
        const int r  = tid >> 2;
        const int c0 = (tid & 3) * 16;
        const float* src = Wm + (size_t)(be * 64 + r) * 512 + bd * 64 + c0;
#pragma unroll
        for (int j = 0; j < 16; j += 4) {
            const float4 v = *reinterpret_cast<const float4*>(src + j);
            tile[r][c0 + j]     = v.x;
            tile[r][c0 + j + 1] = v.y;
            tile[r][c0 + j + 2] = v.z;
            tile[r][c0 + j + 3] = v.w;
        }
        __syncthreads();
        const int dd = tid >> 2;
        const int e0 = (tid & 3) * 16;
        half8 h0, h1;
#pragma unroll
        for (int j = 0; j < 8; ++j)  h0[j] = (_Float16)tile[e0 + j][dd];
#pragma unroll
        for (int j = 0; j < 8; ++j)  h1[j] = (_Float16)tile[e0 + 8 + j][dd];
        _Float16* dst = Bt + (size_t)(bd * 64 + dd) * 512 + be * 64 + e0;
        *reinterpret_cast<half8*>(dst)     = h0;
        *reinterpret_cast<half8*>(dst + 8) = h1;
    }
}

// ---- GEMM + tanh + proj-dot -> spart[8][M] ----
// Round-9 structure, prefetch deepened 1 -> 2 tiles (3 LDS buffers, 72 KB,
// still 2 blk/CU at 512 blocks). Per-thread 6 loads/tile; steady-state wait
// vmcnt(12) = 2 newer tiles in flight, current tile retired. Round-9's
// 1-deep prefetch gave each tile only ~1 compute-period (~200 cy) to cover
// ~500-900 cy L2/HBM latency -> exposed stall each iteration.
__global__ __launch_bounds__(256) void gemm_scores(
    const _Float16* __restrict__ Ah, const _Float16* __restrict__ Bt,
    const float* __restrict__ proj, float* __restrict__ spart)
{
    __shared__ char lds_buf[73728]; // 3 bufs x [A 8K | B 16K]

    const int tid  = threadIdx.x;
    const int lane = tid & 63;
    const int wv   = tid >> 6;
    const int wm   = wv >> 1;
    const int wn   = wv & 1;
    const int hi   = lane >> 5;
    const int l31  = lane & 31;
    const int l7   = lane & 7;

    const int bid  = blockIdx.x;
    const int wgid = (bid & 7) * 64 + (bid >> 3); // XCD-aware swizzle
    const int mb   = wgid >> 2;
    const int nb   = wgid & 3;
    const int m0   = mb * 64;
    const int n0   = nb * 128;

    const int wbase = __builtin_amdgcn_readfirstlane(tid & ~63);

    f32x16 acc0 = {}, acc1 = {};

    auto stage = [&](int bufi, int kt) {
        char* abase = lds_buf + bufi * 24576;
        char* bbase = abase + 8192;
        const int kbase = kt * 64;
#pragma unroll
        for (int i = 0; i < 2; ++i) {
            const int c   = i * 256 + tid;
            const int row = c >> 3;
            const int ch  = c & 7;
            const int koff = kbase + ((ch ^ (row & 7)) << 3);
            gload16(Ah + (size_t)(m0 + row) * 512 + koff,
                    abase + (size_t)(i * 256 + wbase) * 16);
        }
#pragma unroll
        for (int i = 0; i < 4; ++i) {
            const int c   = i * 256 + tid;
            const int row = c >> 3;
            const int ch  = c & 7;
            const int koff = kbase + ((ch ^ (row & 7)) << 3);
            gload16(Bt + (size_t)(n0 + row) * 512 + koff,
                    bbase + (size_t)(i * 256 + wbase) * 16);
        }
    };

    // prologue: tiles 0 and 1 in flight (12 loads/thread outstanding)
    stage(0, 0);
    stage(1, 1);

    const int rowA  = wm * 32 + l31;
    const int colB0 = wn * 64 + l31;
    const int colB1 = colB0 + 32;

#pragma unroll
    for (int kt = 0; kt < 8; ++kt) {
        if (kt < 6) {
            stage((kt + 2) % 3, kt + 2);  // +6 loads: tiles kt+1, kt+2 in flight
            asm volatile("s_waitcnt vmcnt(12)" ::: "memory"); // tile kt retired
        } else if (kt == 6) {
            asm volatile("s_waitcnt vmcnt(6)" ::: "memory");  // tile 6 retired
        } else {
            asm volatile("s_waitcnt vmcnt(0)" ::: "memory");  // tile 7 retired
        }
        __syncthreads(); // all threads' DMA for buf[kt%3] complete

        const char* Ab = lds_buf + (kt % 3) * 24576;
        const char* Bb = Ab + 8192;

        half8 af[4], bf0[4], bf1[4];
#pragma unroll
        for (int s = 0; s < 4; ++s) {
            const int ch = ((2 * s + hi) ^ l7) << 4;
            af[s]  = *reinterpret_cast<const half8*>(Ab + rowA  * 128 + ch);
            bf0[s] = *reinterpret_cast<const half8*>(Bb + colB0 * 128 + ch);
            bf1[s] = *reinterpret_cast<const half8*>(Bb + colB1 * 128 + ch);
        }
        __builtin_amdgcn_s_setprio(1);
#pragma unroll
        for (int s = 0; s < 4; ++s) {
            acc0 = __builtin_amdgcn_mfma_f32_32x32x16_f16(af[s], bf0[s], acc0, 0, 0, 0);
            acc1 = __builtin_amdgcn_mfma_f32_32x32x16_f16(af[s], bf1[s], acc1, 0, 0, 0);
        }
        __builtin_amdgcn_s_setprio(0);

        __syncthreads(); // reads of buf[kt%3] done before iter kt+1 restages it
    }

    const float pj0 = proj[n0 + wn * 64 + l31];
    const float pj1 = proj[n0 + wn * 64 + 32 + l31];
    float* sp = spart + (size_t)(nb * 2 + wn) * M;

#pragma unroll
    for (int reg = 0; reg < 16; ++reg) {
        float v0 = fast_tanh(acc0[reg]) * pj0 + fast_tanh(acc1[reg]) * pj1;
#pragma unroll
        for (int msk = 1; msk < 32; msk <<= 1)
            v0 += __shfl_xor(v0, msk, 64);
        if (l31 == 0) {
            const int rl = (reg & 3) + 8 * (reg >> 2) + 4 * hi;
            sp[m0 + wm * 32 + rl] = v0;
        }
    }
}

// ---- attend: round-9 v2 verbatim (16-row halves, LDS window staging) ----
__global__ __launch_bounds__(256) void attend_kernel(
    const float* __restrict__ X, const _Float16* __restrict__ Ah,
    const float* __restrict__ spart, float* __restrict__ out)
{
    __shared__ char lds[49152];
    _Float16* W_lds = reinterpret_cast<_Float16*>(lds);      // 47*512 fp16
    float*    p_lds = reinterpret_cast<float*>(lds + 48128); // 47 floats

    const int vb  = blockIdx.x;
    const int tid = threadIdx.x;
    const int ih  = vb & 1;
    const int b   = (vb >> 1) & 7;
    const int ig  = vb >> 4;
    const int i0  = ig * 32 + ih * 16;

    if (ig == 0) { // outputs < 32: exact fp32 passthrough
        const float4* X4 = reinterpret_cast<const float4*>(X);
        float4* O4 = reinterpret_cast<float4*>(out);
        for (int idx = tid; idx < 16 * 128; idx += 256) {
            const int r = idx >> 7;
            const int c = idx & 127;
            const size_t off = (size_t)((i0 + r) * 8 + b) * 128 + c;
            O4[off] = X4[off];
        }
        return;
    }

    const int tau0 = i0 - 32;
    const int lane = tid & 63;
    const int wbase = __builtin_amdgcn_readfirstlane(tid & ~63);

    // stage 47 window rows -> W_lds (3008 x 16B chunks; 3008 % 64 == 0)
    {
        const _Float16* src = Ah + (size_t)(tau0 * 8 + b) * 512;
#pragma unroll
        for (int it = 0; it < 12; ++it) {
            const int cbase = it * 256 + wbase;   // wave-uniform chunk base
            if (cbase < 3008) {
                const int c  = cbase + lane;
                const int r  = c >> 6;
                const int ch = c & 63;
                gload16(src + (size_t)r * 4096 + ch * 8,
                        (char*)W_lds + (size_t)cbase * 16);
            }
        }
    }

    // softmax weights for lt in [0,47)
    const int bj = tid & 7;
#pragma unroll
    for (int half = 0; half < 2; ++half) {
        const int lt = (tid >> 3) + half * 32;
        if (lt < 47) {
            float s = 0.f;
#pragma unroll
            for (int g = 0; g < 8; ++g)
                s += spart[(size_t)g * M + (size_t)(tau0 + lt) * 8 + bj];
            float mx = s;
#pragma unroll
            for (int msk = 1; msk < 8; msk <<= 1)
                mx = fmaxf(mx, __shfl_xor(mx, msk, 64));
            const float e = __expf(s - mx);
            float sum = e;
#pragma unroll
            for (int msk = 1; msk < 8; msk <<= 1)
                sum += __shfl_xor(sum, msk, 64);
            if (bj == b) p_lds[lt] = e / sum;
        }
    }

    asm volatile("s_waitcnt vmcnt(0)" ::: "memory");
    __syncthreads();

    // wave rg owns output rows i0+u0+q, q=0..3 (u0 = rg*4); window rows
    // lt = u0+u, u in [0,35); row feeds output q iff k = u-q in [0,32).
    const int rg = tid >> 6;
    const int u0 = rg * 4;
    float acc[4][8];
#pragma unroll
    for (int q = 0; q < 4; ++q)
#pragma unroll
        for (int j = 0; j < 8; ++j) acc[q][j] = 0.f;

    auto apply = [&](int u, int qlo, int qhi) {
        const int lt = u0 + u;
        const float pw = p_lds[lt];
        const half8 h = *reinterpret_cast<const half8*>(
            W_lds + (size_t)lt * 512 + lane * 8);
        float hf[8];
#pragma unroll
        for (int j = 0; j < 8; ++j) hf[j] = (float)h[j];
        for (int q = qlo; q <= qhi; ++q)
#pragma unroll
            for (int j = 0; j < 8; ++j)
                acc[q][j] = fmaf(pw, hf[j], acc[q][j]);
    };

#pragma unroll
    for (int u = 0; u < 3; ++u)  apply(u, 0, u);        // head: q <= u
    for (int u = 3; u < 32; ++u) apply(u, 0, 3);        // body: all q
#pragma unroll
    for (int u = 32; u < 35; ++u) apply(u, u - 31, 3);  // tail: q >= u-31

#pragma unroll
    for (int q = 0; q < 4; ++q) {
        float4* O4 = reinterpret_cast<float4*>(
            out + (size_t)((i0 + u0 + q) * 8 + b) * 512 + lane * 8);
        O4[0] = float4{acc[q][0], acc[q][1], acc[q][2], acc[q][3]};
        O4[1] = float4{acc[q][4], acc[q][5], acc[q][6], acc[q][7]};
    }
}

extern "C" void kernel_launch(void* const* d_in, const int* in_sizes, int n_in,
                              void* d_out, int out_size, void* d_ws, size_t ws_size,
                              hipStream_t stream)
{
    const float* X    = (const float*)d_in[0];
    const float* Wm   = (const float*)d_in[1];
    const float* proj = (const float*)d_in[2];
    float* out = (float*)d_out;

    _Float16* Ah   = (_Float16*)d_ws;              // 8 MB
    _Float16* Bt   = Ah + (size_t)M * D;           // 0.5 MB
    float*    sprt = (float*)(Bt + (size_t)D * D); // 8*M floats

    prep_merged<<<2048, 256, 0, stream>>>(X, Wm, Ah, Bt);
    gemm_scores<<<512, 256, 0, stream>>>(Ah, Bt, proj, sprt);
    attend_kernel<<<(T / W) * B * 2, 256, 0, stream>>>(X, Ah, sprt, out);
}

// Round 13
// 37.003 us; speedup vs baseline: 1.1016x; 1.0133x over previous
//
#include <hip/hip_runtime.h>
#include <cstdint>

namespace {
constexpr int T = 1024;
constexpr int B = 8;
constexpr int D = 512;
constexpr int W = 32;
constexpr int M = T * B; // 8192 rows (t*B+b)
}

using half8  = __attribute__((ext_vector_type(8))) _Float16;
using f32x16 = __attribute__((ext_vector_type(16))) float;

__device__ __forceinline__ void gload16(const void* g, void* l) {
    __builtin_amdgcn_global_load_lds(
        (const __attribute__((address_space(1))) void*)g,
        (__attribute__((address_space(3))) void*)l, 16, 0, 0);
}

__device__ __forceinline__ float fast_tanh(float x) {
    float e = __expf(2.f * x);
    return 1.f - 2.f / (e + 1.f);
}

// ---- prep: X fp32 -> Ah fp16 [M][D]; W -> Bt^T (blocks 0..63).
// Grid shrunk 2048 -> 512 blocks (4 chunks/thread, grid-stride): same
// 24.5 MB of traffic, 1/4 the dispatch ramp + tail before gemm can start.
__global__ __launch_bounds__(256) void prep_merged(
    const float* __restrict__ X, const float* __restrict__ Wm,
    _Float16* __restrict__ Ah, _Float16* __restrict__ Bt)
{
    __shared__ float tile[64][65];
    const int tid = threadIdx.x;
    const int bid = blockIdx.x;

    {
        const float4* X4 = reinterpret_cast<const float4*>(X);
#pragma unroll
        for (int it = 0; it < 4; ++it) {
            const int c = bid * 256 + tid + it * 131072; // 512*256 threads
            const float4 v0 = X4[(size_t)c * 2];
            const float4 v1 = X4[(size_t)c * 2 + 1];
            half8 h;
            h[0] = (_Float16)v0.x; h[1] = (_Float16)v0.y; h[2] = (_Float16)v0.z; h[3] = (_Float16)v0.w;
            h[4] = (_Float16)v1.x; h[5] = (_Float16)v1.y; h[6] = (_Float16)v1.z; h[7] = (_Float16)v1.w;
            *reinterpret_cast<half8*>(Ah + (size_t)c * 8) = h;
        }
    }

    if (bid < 64) {
        const int bd = bid & 7;
        const int be = bid >> 3;
        const int r  = tid >> 2;
        const int c0 = (tid & 3) * 16;
        const float* src = Wm + (size_t)(be * 64 + r) * 512 + bd * 64 + c0;
#pragma unroll
        for (int j = 0; j < 16; j += 4) {
            const float4 v = *reinterpret_cast<const float4*>(src + j);
            tile[r][c0 + j]     = v.x;
            tile[r][c0 + j + 1] = v.y;
            tile[r][c0 + j + 2] = v.z;
            tile[r][c0 + j + 3] = v.w;
        }
        __syncthreads();
        const int dd = tid >> 2;
        const int e0 = (tid & 3) * 16;
        half8 h0, h1;
#pragma unroll
        for (int j = 0; j < 8; ++j)  h0[j] = (_Float16)tile[e0 + j][dd];
#pragma unroll
        for (int j = 0; j < 8; ++j)  h1[j] = (_Float16)tile[e0 + 8 + j][dd];
        _Float16* dst = Bt + (size_t)(bd * 64 + dd) * 512 + be * 64 + e0;
        *reinterpret_cast<half8*>(dst)     = h0;
        *reinterpret_cast<half8*>(dst + 8) = h1;
    }
}

// ---- GEMM + tanh + proj-dot -> spart[8][M] ----
// 3-buffer rotation (validated round 12) reordered to ONE barrier per
// iteration: vmcnt(6) -> barrier -> stage(kt+2) -> ds_read/MFMA.
// WAR-safe: stage(kt+2) overwrites buf[(kt-1)%3]; all its readers passed
// this iteration's barrier (syncthreads drains lgkmcnt). Per-wave vmcnt(6)
// before the barrier retires exactly tile kt (12 outstanding -> 6).
// Tile 64x128, 512 blocks, 72 KB LDS, 2 blk/CU.
__global__ __launch_bounds__(256) void gemm_scores(
    const _Float16* __restrict__ Ah, const _Float16* __restrict__ Bt,
    const float* __restrict__ proj, float* __restrict__ spart)
{
    __shared__ char lds_buf[73728]; // 3 bufs x [A 8K | B 16K]

    const int tid  = threadIdx.x;
    const int lane = tid & 63;
    const int wv   = tid >> 6;
    const int wm   = wv >> 1;
    const int wn   = wv & 1;
    const int hi   = lane >> 5;
    const int l31  = lane & 31;
    const int l7   = lane & 7;

    const int bid  = blockIdx.x;
    const int wgid = (bid & 7) * 64 + (bid >> 3); // XCD-aware swizzle
    const int mb   = wgid >> 2;
    const int nb   = wgid & 3;
    const int m0   = mb * 64;
    const int n0   = nb * 128;

    const int wbase = __builtin_amdgcn_readfirstlane(tid & ~63);

    f32x16 acc0 = {}, acc1 = {};

    auto stage = [&](int bufi, int kt) {
        char* abase = lds_buf + bufi * 24576;
        char* bbase = abase + 8192;
        const int kbase = kt * 64;
#pragma unroll
        for (int i = 0; i < 2; ++i) {
            const int c   = i * 256 + tid;
            const int row = c >> 3;
            const int ch  = c & 7;
            const int koff = kbase + ((ch ^ (row & 7)) << 3);
            gload16(Ah + (size_t)(m0 + row) * 512 + koff,
                    abase + (size_t)(i * 256 + wbase) * 16);
        }
#pragma unroll
        for (int i = 0; i < 4; ++i) {
            const int c   = i * 256 + tid;
            const int row = c >> 3;
            const int ch  = c & 7;
            const int koff = kbase + ((ch ^ (row & 7)) << 3);
            gload16(Bt + (size_t)(n0 + row) * 512 + koff,
                    bbase + (size_t)(i * 256 + wbase) * 16);
        }
    };

    // prologue: tiles 0 and 1 in flight (12 loads/thread outstanding)
    stage(0, 0);
    stage(1, 1);

    const int rowA  = wm * 32 + l31;
    const int colB0 = wn * 64 + l31;
    const int colB1 = colB0 + 32;

#pragma unroll
    for (int kt = 0; kt < 8; ++kt) {
        if (kt < 7) {
            asm volatile("s_waitcnt vmcnt(6)" ::: "memory"); // tile kt retired
        } else {
            asm volatile("s_waitcnt vmcnt(0)" ::: "memory"); // tile 7 retired
        }
        __syncthreads(); // every wave's tile-kt DMA done; iter kt-1 reads done

        if (kt < 6) stage((kt + 2) % 3, kt + 2); // overwrites buf[(kt-1)%3]

        const char* Ab = lds_buf + (kt % 3) * 24576;
        const char* Bb = Ab + 8192;

        half8 af[4], bf0[4], bf1[4];
#pragma unroll
        for (int s = 0; s < 4; ++s) {
            const int ch = ((2 * s + hi) ^ l7) << 4;
            af[s]  = *reinterpret_cast<const half8*>(Ab + rowA  * 128 + ch);
            bf0[s] = *reinterpret_cast<const half8*>(Bb + colB0 * 128 + ch);
            bf1[s] = *reinterpret_cast<const half8*>(Bb + colB1 * 128 + ch);
        }
        __builtin_amdgcn_s_setprio(1);
#pragma unroll
        for (int s = 0; s < 4; ++s) {
            acc0 = __builtin_amdgcn_mfma_f32_32x32x16_f16(af[s], bf0[s], acc0, 0, 0, 0);
            acc1 = __builtin_amdgcn_mfma_f32_32x32x16_f16(af[s], bf1[s], acc1, 0, 0, 0);
        }
        __builtin_amdgcn_s_setprio(0);
    }

    const float pj0 = proj[n0 + wn * 64 + l31];
    const float pj1 = proj[n0 + wn * 64 + 32 + l31];
    float* sp = spart + (size_t)(nb * 2 + wn) * M;

#pragma unroll
    for (int reg = 0; reg < 16; ++reg) {
        float v0 = fast_tanh(acc0[reg]) * pj0 + fast_tanh(acc1[reg]) * pj1;
#pragma unroll
        for (int msk = 1; msk < 32; msk <<= 1)
            v0 += __shfl_xor(v0, msk, 64);
        if (l31 == 0) {
            const int rl = (reg & 3) + 8 * (reg >> 2) + 4 * hi;
            sp[m0 + wm * 32 + rl] = v0;
        }
    }
}

// ---- attend: round-9 v2 verbatim (16-row halves, LDS window staging) ----
__global__ __launch_bounds__(256) void attend_kernel(
    const float* __restrict__ X, const _Float16* __restrict__ Ah,
    const float* __restrict__ spart, float* __restrict__ out)
{
    __shared__ char lds[49152];
    _Float16* W_lds = reinterpret_cast<_Float16*>(lds);      // 47*512 fp16
    float*    p_lds = reinterpret_cast<float*>(lds + 48128); // 47 floats

    const int vb  = blockIdx.x;
    const int tid = threadIdx.x;
    const int ih  = vb & 1;
    const int b   = (vb >> 1) & 7;
    const int ig  = vb >> 4;
    const int i0  = ig * 32 + ih * 16;

    if (ig == 0) { // outputs < 32: exact fp32 passthrough
        const float4* X4 = reinterpret_cast<const float4*>(X);
        float4* O4 = reinterpret_cast<float4*>(out);
        for (int idx = tid; idx < 16 * 128; idx += 256) {
            const int r = idx >> 7;
            const int c = idx & 127;
            const size_t off = (size_t)((i0 + r) * 8 + b) * 128 + c;
            O4[off] = X4[off];
        }
        return;
    }

    const int tau0 = i0 - 32;
    const int lane = tid & 63;
    const int wbase = __builtin_amdgcn_readfirstlane(tid & ~63);

    // stage 47 window rows -> W_lds (3008 x 16B chunks; 3008 % 64 == 0)
    {
        const _Float16* src = Ah + (size_t)(tau0 * 8 + b) * 512;
#pragma unroll
        for (int it = 0; it < 12; ++it) {
            const int cbase = it * 256 + wbase;   // wave-uniform chunk base
            if (cbase < 3008) {
                const int c  = cbase + lane;
                const int r  = c >> 6;
                const int ch = c & 63;
                gload16(src + (size_t)r * 4096 + ch * 8,
                        (char*)W_lds + (size_t)cbase * 16);
            }
        }
    }

    // softmax weights for lt in [0,47)
    const int bj = tid & 7;
#pragma unroll
    for (int half = 0; half < 2; ++half) {
        const int lt = (tid >> 3) + half * 32;
        if (lt < 47) {
            float s = 0.f;
#pragma unroll
            for (int g = 0; g < 8; ++g)
                s += spart[(size_t)g * M + (size_t)(tau0 + lt) * 8 + bj];
            float mx = s;
#pragma unroll
            for (int msk = 1; msk < 8; msk <<= 1)
                mx = fmaxf(mx, __shfl_xor(mx, msk, 64));
            const float e = __expf(s - mx);
            float sum = e;
#pragma unroll
            for (int msk = 1; msk < 8; msk <<= 1)
                sum += __shfl_xor(sum, msk, 64);
            if (bj == b) p_lds[lt] = e / sum;
        }
    }

    asm volatile("s_waitcnt vmcnt(0)" ::: "memory");
    __syncthreads();

    // wave rg owns output rows i0+u0+q, q=0..3 (u0 = rg*4); window rows
    // lt = u0+u, u in [0,35); row feeds output q iff k = u-q in [0,32).
    const int rg = tid >> 6;
    const int u0 = rg * 4;
    float acc[4][8];
#pragma unroll
    for (int q = 0; q < 4; ++q)
#pragma unroll
        for (int j = 0; j < 8; ++j) acc[q][j] = 0.f;

    auto apply = [&](int u, int qlo, int qhi) {
        const int lt = u0 + u;
        const float pw = p_lds[lt];
        const half8 h = *reinterpret_cast<const half8*>(
            W_lds + (size_t)lt * 512 + lane * 8);
        float hf[8];
#pragma unroll
        for (int j = 0; j < 8; ++j) hf[j] = (float)h[j];
        for (int q = qlo; q <= qhi; ++q)
#pragma unroll
            for (int j = 0; j < 8; ++j)
                acc[q][j] = fmaf(pw, hf[j], acc[q][j]);
    };

#pragma unroll
    for (int u = 0; u < 3; ++u)  apply(u, 0, u);        // head: q <= u
    for (int u = 3; u < 32; ++u) apply(u, 0, 3);        // body: all q
#pragma unroll
    for (int u = 32; u < 35; ++u) apply(u, u - 31, 3);  // tail: q >= u-31

#pragma unroll
    for (int q = 0; q < 4; ++q) {
        float4* O4 = reinterpret_cast<float4*>(
            out + (size_t)((i0 + u0 + q) * 8 + b) * 512 + lane * 8);
        O4[0] = float4{acc[q][0], acc[q][1], acc[q][2], acc[q][3]};
        O4[1] = float4{acc[q][4], acc[q][5], acc[q][6], acc[q][7]};
    }
}

extern "C" void kernel_launch(void* const* d_in, const int* in_sizes, int n_in,
                              void* d_out, int out_size, void* d_ws, size_t ws_size,
                              hipStream_t stream)
{
    const float* X    = (const float*)d_in[0];
    const float* Wm   = (const float*)d_in[1];
    const float* proj = (const float*)d_in[2];
    float* out = (float*)d_out;

    _Float16* Ah   = (_Float16*)d_ws;              // 8 MB
    _Float16* Bt   = Ah + (size_t)M * D;           // 0.5 MB
    float*    sprt = (float*)(Bt + (size_t)D * D); // 8*M floats

    prep_merged<<<512, 256, 0, stream>>>(X, Wm, Ah, Bt);
    gemm_scores<<<512, 256, 0, stream>>>(Ah, Bt, proj, sprt);
    attend_kernel<<<(T / W) * B * 2, 256, 0, stream>>>(X, Ah, sprt, out);
}